// Round 2
// baseline (299.696 us; speedup 1.0000x reference)
//
#include <hip/hip_runtime.h>
#include <cstdint>
#include <cstddef>

typedef int int32x4 __attribute__((ext_vector_type(4)));

#define AS1 __attribute__((address_space(1)))
#define AS3 __attribute__((address_space(3)))

__device__ __forceinline__ void gload_lds16(const void* g, void* l) {
    __builtin_amdgcn_global_load_lds((const AS1 void*)g, (AS3 void*)l, 16, 0, 0);
}

// ---------------------------------------------------------------------------
// Kernel 1: x (fp32, int8-valued) -> A8 (int8) + row sums rs.
// One block per row. Thread t packs 16 consecutive bytes -> one int4 store.
// ---------------------------------------------------------------------------
__global__ __launch_bounds__(256) void quant_x(const float* __restrict__ x,
                                               signed char* __restrict__ A8,
                                               int* __restrict__ rs) {
    const int row = blockIdx.x;
    const int t = threadIdx.x;
    const float4* xr = (const float4*)(x + (size_t)row * 4096) + t * 4;
    int w[4];
    int s = 0;
#pragma unroll
    for (int i = 0; i < 4; i++) {
        float4 v = xr[i];
        int a0 = (int)v.x, a1 = (int)v.y, a2 = (int)v.z, a3 = (int)v.w;
        s += a0 + a1 + a2 + a3;
        w[i] = (a0 & 0xFF) | ((a1 & 0xFF) << 8) | ((a2 & 0xFF) << 16) | (a3 << 24);
    }
    *(int32x4*)(A8 + (size_t)row * 4096 + t * 16) = int32x4{w[0], w[1], w[2], w[3]};
    // wave reduce then cross-wave via LDS
#pragma unroll
    for (int off = 32; off > 0; off >>= 1) s += __shfl_down(s, off);
    __shared__ int wsum[4];
    if ((t & 63) == 0) wsum[t >> 6] = s;
    __syncthreads();
    if (t == 0) rs[row] = wsum[0] + wsum[1] + wsum[2] + wsum[3];
}

// ---------------------------------------------------------------------------
// Kernel 2: y (fp32, uint8-valued) -> B8T (int8 transposed, y-128) + col sums
// sy (fused, via LDS partial sums + global atomics; sy pre-zeroed by memset).
// Block tile: 256(k) x 64(n). Thread: 16(k) x 4(n) micro-tile, register
// transpose, 16 B/lane int4 stores. Grid (64 n-tiles, 16 k-tiles).
// ---------------------------------------------------------------------------
__global__ __launch_bounds__(256) void quant_y(const float* __restrict__ y,
                                               signed char* __restrict__ B8T,
                                               int* __restrict__ sy) {
    const int nt = blockIdx.x * 64;
    const int kt = blockIdx.y * 256;
    const int t = threadIdx.x;
    const int kg = t >> 4;        // 0..15 -> k-offset kg*16
    const int ng = t & 15;        // 0..15 -> n-offset ng*4

    __shared__ int ssum[64];
    if (t < 64) ssum[t] = 0;
    __syncthreads();

    int w[4][4] = {};   // w[j][i>>2] : packed bytes for output row ng*4+j
    int s[4] = {};
#pragma unroll
    for (int i = 0; i < 16; i++) {
        float4 v = *(const float4*)(y + (size_t)(kt + kg * 16 + i) * 4096 + nt + ng * 4);
        int b0 = (int)v.x - 128, b1 = (int)v.y - 128, b2 = (int)v.z - 128, b3 = (int)v.w - 128;
        s[0] += b0; s[1] += b1; s[2] += b2; s[3] += b3;
        const int sh = (i & 3) * 8;
        w[0][i >> 2] |= (b0 & 0xFF) << sh;
        w[1][i >> 2] |= (b1 & 0xFF) << sh;
        w[2][i >> 2] |= (b2 & 0xFF) << sh;
        w[3][i >> 2] |= (b3 & 0xFF) << sh;
    }
#pragma unroll
    for (int j = 0; j < 4; j++) {
        *(int32x4*)(B8T + (size_t)(nt + ng * 4 + j) * 4096 + kt + kg * 16) =
            int32x4{w[j][0], w[j][1], w[j][2], w[j][3]};
        atomicAdd(&ssum[ng * 4 + j], s[j]);
    }
    __syncthreads();
    if (t < 64) atomicAdd(&sy[nt + t], ssum[t]);
}

// ---------------------------------------------------------------------------
// Kernel 3: int8 GEMM. 128x128 block tile, BK=64, 4 waves (2x2), each wave
// 4x4 grid of 16x16x64 i8 MFMAs. LDS tiles stored in FRAGMENT ORDER:
// offset = group*1024 + lane*16 (group = row>>4), so fragment ds_read_b128
// is lane-ascending contiguous -> zero bank conflicts. Staging keeps the
// mandatory dst = base + tid*16 and permutes the global source instead.
// Epilogue: C = 7.5e-4 * (P - 32*rs[m] + 66*sy[n] - 8650752)
// ---------------------------------------------------------------------------
__global__ __launch_bounds__(256) void gemm_i8(const signed char* __restrict__ A8,
                                               const signed char* __restrict__ B8T,
                                               const int* __restrict__ rs,
                                               const int* __restrict__ sy,
                                               float* __restrict__ C) {
    __shared__ __align__(16) signed char As[128 * 64];  // 8 KB, frag-order
    __shared__ __align__(16) signed char Bs[128 * 64];  // 8 KB, frag-order
    const int tid = threadIdx.x;
    const int bm = blockIdx.y * 128;
    const int bn = blockIdx.x * 128;
    const int lane = tid & 63;
    const int wave = tid >> 6;
    const int wm = (wave >> 1) * 64;
    const int wn = (wave & 1) * 64;
    const int r16 = lane & 15;
    const int q = lane >> 4;

    int32x4 acc[4][4] = {};

    // staging source permutation: thread tid -> row (tid>>6)*16 + (tid&15),
    // k-chunk (tid>>4)&3. Wave still covers the same 16 x 64B global segments.
    const int srow = ((tid >> 6) << 4) | (tid & 15);      // 0..63
    const int scol = ((tid >> 4) & 3) * 16;               // 0..48
    const size_t arow  = (size_t)(bm + srow) * 4096 + scol;
    const size_t brow  = (size_t)(bn + srow) * 4096 + scol;
    const size_t arow2 = arow + (size_t)64 * 4096;
    const size_t brow2 = brow + (size_t)64 * 4096;
    signed char* a_dst = As + tid * 16;
    signed char* b_dst = Bs + tid * 16;

    const int wmg = wm >> 4;  // wave's row-group base (0 or 4)
    const int wng = wn >> 4;

    for (int kt = 0; kt < 4096; kt += 64) {
        gload_lds16(A8 + arow + kt, a_dst);
        gload_lds16(A8 + arow2 + kt, a_dst + 4096);
        gload_lds16(B8T + brow + kt, b_dst);
        gload_lds16(B8T + brow2 + kt, b_dst + 4096);
        __syncthreads();

        int32x4 af[4], bf[4];
#pragma unroll
        for (int i = 0; i < 4; i++)
            af[i] = *(const int32x4*)(As + (wmg + i) * 1024 + lane * 16);
#pragma unroll
        for (int j = 0; j < 4; j++)
            bf[j] = *(const int32x4*)(Bs + (wng + j) * 1024 + lane * 16);

#pragma unroll
        for (int i = 0; i < 4; i++)
#pragma unroll
            for (int j = 0; j < 4; j++)
                acc[i][j] = __builtin_amdgcn_mfma_i32_16x16x64_i8(af[i], bf[j], acc[i][j], 0, 0, 0);
        __syncthreads();
    }

    // Epilogue. C/D layout: col = lane&15, row = (lane>>4)*4 + reg
#pragma unroll
    for (int i = 0; i < 4; i++) {
#pragma unroll
        for (int r = 0; r < 4; r++) {
            const int gm = bm + wm + i * 16 + q * 4 + r;
            const int rcorr = -32 * rs[gm] - 8650752;
#pragma unroll
            for (int j = 0; j < 4; j++) {
                const int gn = bn + wn + j * 16 + r16;
                const int v = acc[i][j][r] + rcorr + 66 * sy[gn];
                C[(size_t)gm * 4096 + gn] = 7.5e-4f * (float)v;
            }
        }
    }
}

// ---------------------------------------------------------------------------
extern "C" void kernel_launch(void* const* d_in, const int* in_sizes, int n_in,
                              void* d_out, int out_size, void* d_ws, size_t ws_size,
                              hipStream_t stream) {
    const float* x = (const float*)d_in[0];  // [4096,4096] int8-valued
    const float* y = (const float*)d_in[1];  // [4096,4096] uint8-valued
    float* out = (float*)d_out;

    char* ws = (char*)d_ws;
    signed char* A8  = (signed char*)ws;                         // 16 MiB
    signed char* B8T = (signed char*)(ws + (16u << 20));         // 16 MiB
    int* rs = (int*)(ws + (32u << 20));                          // 16 KiB
    int* sy = (int*)(ws + (32u << 20) + (16u << 10));            // 16 KiB

    hipMemsetAsync(sy, 0, 4096 * sizeof(int), stream);
    quant_x<<<4096, 256, 0, stream>>>(x, A8, rs);
    quant_y<<<dim3(64, 16), 256, 0, stream>>>(y, B8T, sy);
    gemm_i8<<<dim3(32, 32), 256, 0, stream>>>(A8, B8T, rs, sy, out);
}

// Round 3
// 252.860 us; speedup vs baseline: 1.1852x; 1.1852x over previous
//
#include <hip/hip_runtime.h>
#include <cstdint>
#include <cstddef>

typedef int int32x4 __attribute__((ext_vector_type(4)));

#define AS1 __attribute__((address_space(1)))
#define AS3 __attribute__((address_space(3)))

__device__ __forceinline__ void gload_lds16(const void* g, void* l) {
    __builtin_amdgcn_global_load_lds((const AS1 void*)g, (AS3 void*)l, 16, 0, 0);
}

// ---------------------------------------------------------------------------
// Kernel 1: x (fp32, int8-valued) -> A8 (int8) + row sums rs.
// One block per row. Fully coalesced: loads 1KB/wave-instr, stores 256B.
// ---------------------------------------------------------------------------
__global__ __launch_bounds__(256) void quant_x(const float* __restrict__ x,
                                               signed char* __restrict__ A8,
                                               int* __restrict__ rs) {
    const int row = blockIdx.x;
    const int t = threadIdx.x;
    const float4* xr = (const float4*)(x + (size_t)row * 4096);
    char4* ar = (char4*)(A8 + (size_t)row * 4096);
    int s = 0;
#pragma unroll
    for (int i = 0; i < 4; i++) {
        const int idx = i * 256 + t;
        float4 v = xr[idx];
        int a0 = (int)v.x, a1 = (int)v.y, a2 = (int)v.z, a3 = (int)v.w;
        s += a0 + a1 + a2 + a3;
        char4 c;
        c.x = (signed char)a0; c.y = (signed char)a1;
        c.z = (signed char)a2; c.w = (signed char)a3;
        ar[idx] = c;
    }
#pragma unroll
    for (int off = 32; off > 0; off >>= 1) s += __shfl_down(s, off);
    __shared__ int wsum[4];
    if ((t & 63) == 0) wsum[t >> 6] = s;
    __syncthreads();
    if (t == 0) rs[row] = wsum[0] + wsum[1] + wsum[2] + wsum[3];
}

// ---------------------------------------------------------------------------
// Kernel 2: y (fp32, uint8-valued) -> B8T (int8 transposed, y-128) + col sums
// sy (fused; sy pre-zeroed by memset). 64k x 64n tile per block via LDS
// byte-transpose (pitch 68 -> <=2-way banks). Loads: 256B-contiguous per
// 16-lane group. Stores: int4, lanes 0-3 cover one row's 64B IN ORDER.
// ---------------------------------------------------------------------------
__global__ __launch_bounds__(256) void quant_y(const float* __restrict__ y,
                                               signed char* __restrict__ B8T,
                                               int* __restrict__ sy) {
    __shared__ __align__(16) signed char tile[64 * 68];  // tile[n*68 + k]
    __shared__ int ssum[64];
    const int nt = blockIdx.x * 64;
    const int kt = blockIdx.y * 64;
    const int t = threadIdx.x;
    if (t < 64) ssum[t] = 0;
    __syncthreads();

    const int r0 = t >> 4;         // k-offset within tile group
    const int c4 = (t & 15) * 4;   // n-offset (4 cols per thread)
    int s0 = 0, s1 = 0, s2 = 0, s3 = 0;
#pragma unroll
    for (int i = 0; i < 4; i++) {
        const int k = i * 16 + r0;
        float4 v = *(const float4*)(y + (size_t)(kt + k) * 4096 + nt + c4);
        int b0 = (int)v.x - 128, b1 = (int)v.y - 128;
        int b2 = (int)v.z - 128, b3 = (int)v.w - 128;
        s0 += b0; s1 += b1; s2 += b2; s3 += b3;
        tile[(c4 + 0) * 68 + k] = (signed char)b0;
        tile[(c4 + 1) * 68 + k] = (signed char)b1;
        tile[(c4 + 2) * 68 + k] = (signed char)b2;
        tile[(c4 + 3) * 68 + k] = (signed char)b3;
    }
    atomicAdd(&ssum[c4 + 0], s0);
    atomicAdd(&ssum[c4 + 1], s1);
    atomicAdd(&ssum[c4 + 2], s2);
    atomicAdd(&ssum[c4 + 3], s3);
    __syncthreads();

    const int n = t >> 2;          // output row within tile
    const int kc = (t & 3) * 16;   // 16B chunk within row
    const signed char* src = tile + n * 68 + kc;
    int32x4 w;
    w.x = *(const int*)(src + 0);
    w.y = *(const int*)(src + 4);
    w.z = *(const int*)(src + 8);
    w.w = *(const int*)(src + 12);
    *(int32x4*)(B8T + (size_t)(nt + n) * 4096 + kt + kc) = w;
    if (t < 64) atomicAdd(&sy[nt + t], ssum[t]);
}

// ---------------------------------------------------------------------------
// Kernel 3: int8 GEMM. 128x128 block tile, BK=64, 4 waves (2x2), each wave
// 4x4 grid of 16x16x64 i8 MFMAs. LDS layout: dense 64B rows with XOR chunk
// swizzle: slot(row,chunk) = chunk ^ ((row>>1)&3). Staging keeps round-1
// adjacent-quad global mapping (row = tid>>2), chunks permuted only within
// each 64B segment. Fragment reads: 2-way banks max (free).
// Epilogue: C = 7.5e-4 * (P - 32*rs[m] + 66*sy[n] - 8650752)
// ---------------------------------------------------------------------------
__global__ __launch_bounds__(256) void gemm_i8(const signed char* __restrict__ A8,
                                               const signed char* __restrict__ B8T,
                                               const int* __restrict__ rs,
                                               const int* __restrict__ sy,
                                               float* __restrict__ C) {
    __shared__ __align__(16) signed char As[128 * 64];  // 8 KB
    __shared__ __align__(16) signed char Bs[128 * 64];  // 8 KB
    const int tid = threadIdx.x;
    const int bm = blockIdx.y * 128;
    const int bn = blockIdx.x * 128;
    const int lane = tid & 63;
    const int wave = tid >> 6;
    const int wm = (wave >> 1) * 64;
    const int wn = (wave & 1) * 64;
    const int r16 = lane & 15;
    const int q = lane >> 4;

    int32x4 acc[4][4] = {};

    // staging: thread tid -> row tid>>2 (adjacent quads), global chunk
    // c = (tid&3) ^ ((tid>>3)&3) lands at phys slot tid&3 (XOR swizzle).
    const int srow = tid >> 2;
    const int scol = ((tid & 3) ^ ((tid >> 3) & 3)) * 16;
    const size_t arow  = (size_t)(bm + srow) * 4096 + scol;
    const size_t brow  = (size_t)(bn + srow) * 4096 + scol;
    const size_t arow2 = arow + (size_t)64 * 4096;
    const size_t brow2 = brow + (size_t)64 * 4096;
    signed char* a_dst = As + tid * 16;
    signed char* b_dst = Bs + tid * 16;

    // fragment read slot: chunk q of row (.. + r16) lives at slot q^((r16>>1)&3)
    const int slot = (q ^ ((r16 >> 1) & 3)) * 16;

    for (int kt = 0; kt < 4096; kt += 64) {
        gload_lds16(A8 + arow + kt, a_dst);
        gload_lds16(A8 + arow2 + kt, a_dst + 4096);
        gload_lds16(B8T + brow + kt, b_dst);
        gload_lds16(B8T + brow2 + kt, b_dst + 4096);
        __syncthreads();

        int32x4 af[4], bf[4];
#pragma unroll
        for (int i = 0; i < 4; i++)
            af[i] = *(const int32x4*)(As + (wm + i * 16 + r16) * 64 + slot);
#pragma unroll
        for (int j = 0; j < 4; j++)
            bf[j] = *(const int32x4*)(Bs + (wn + j * 16 + r16) * 64 + slot);

#pragma unroll
        for (int i = 0; i < 4; i++)
#pragma unroll
            for (int j = 0; j < 4; j++)
                acc[i][j] = __builtin_amdgcn_mfma_i32_16x16x64_i8(af[i], bf[j], acc[i][j], 0, 0, 0);
        __syncthreads();
    }

    // Epilogue. C/D layout: col = lane&15, row = (lane>>4)*4 + reg
#pragma unroll
    for (int i = 0; i < 4; i++) {
#pragma unroll
        for (int r = 0; r < 4; r++) {
            const int gm = bm + wm + i * 16 + q * 4 + r;
            const int rcorr = -32 * rs[gm] - 8650752;
#pragma unroll
            for (int j = 0; j < 4; j++) {
                const int gn = bn + wn + j * 16 + r16;
                const int v = acc[i][j][r] + rcorr + 66 * sy[gn];
                C[(size_t)gm * 4096 + gn] = 7.5e-4f * (float)v;
            }
        }
    }
}

// ---------------------------------------------------------------------------
extern "C" void kernel_launch(void* const* d_in, const int* in_sizes, int n_in,
                              void* d_out, int out_size, void* d_ws, size_t ws_size,
                              hipStream_t stream) {
    const float* x = (const float*)d_in[0];  // [4096,4096] int8-valued
    const float* y = (const float*)d_in[1];  // [4096,4096] uint8-valued
    float* out = (float*)d_out;

    char* ws = (char*)d_ws;
    signed char* A8  = (signed char*)ws;                         // 16 MiB
    signed char* B8T = (signed char*)(ws + (16u << 20));         // 16 MiB
    int* rs = (int*)(ws + (32u << 20));                          // 16 KiB
    int* sy = (int*)(ws + (32u << 20) + (16u << 10));            // 16 KiB

    hipMemsetAsync(sy, 0, 4096 * sizeof(int), stream);
    quant_x<<<4096, 256, 0, stream>>>(x, A8, rs);
    quant_y<<<dim3(64, 64), 256, 0, stream>>>(y, B8T, sy);
    gemm_i8<<<dim3(32, 32), 256, 0, stream>>>(A8, B8T, rs, sy, out);
}